// Round 3
// baseline (174.780 us; speedup 1.0000x reference)
//
#include <hip/hip_runtime.h>

#define L_LEN 32768
#define QMAXF 127.0f
#define TPW 4   // 16-t groups per wave

typedef __attribute__((ext_vector_type(4))) int v4i;
typedef float v4f __attribute__((ext_vector_type(4)));

// unaligned-safe 16B load (float* is only 4B-aligned at t-1)
__device__ inline v4f load4u(const float* p) {
    v4f v;
    __builtin_memcpy(&v, p, 16);
    return v;
}

// wsf layout (floats):
//   [0..1536)    : phase-1 partials [ic][b][k]  (64*8*3)
//   [1536..1728) : rvp[k][ic] = 1/(scl[3*ic+k] * s_x)   (k-major, 64-stride)
//   [1728]       : s_x * s_w
// wsa (byte offset 8192): A fragments, k-major j' = k*64 + ic:
//   dword idx ((mt*3+s)*64 + lane)*4 + d, byte bb = qw[oc=mt*16+(lane&15)][3*(16*(lane>>4)+4*d+bb)+s]

// ---------------- pass 1: per-(ic,b) abs-max partials ----------------
__global__ __launch_bounds__(1024) void actamax_kernel(const float* __restrict__ x,
                                                       float* __restrict__ wsf) {
    const int ic = blockIdx.x, b = blockIdx.y;
    const float4* row = (const float4*)(x + ((size_t)(b*64 + ic) << 15));
    float mA = 0.0f, mNF = 0.0f, mNL = 0.0f;   // all, no-first(t>0), no-last(t<L-1)
    #pragma unroll
    for (int i = 0; i < 8; ++i) {
        int f = threadIdx.x + (i << 10);
        float4 v = row[f];
        float ax = fabsf(v.x), ay = fabsf(v.y), az = fabsf(v.z), aw = fabsf(v.w);
        float m4 = fmaxf(fmaxf(ax, ay), fmaxf(az, aw));
        mA = fmaxf(mA, m4);
        if (f == 0) {
            mNF = fmaxf(mNF, fmaxf(ay, fmaxf(az, aw)));
            mNL = fmaxf(mNL, m4);
        } else if (f == 8191) {
            mNF = fmaxf(mNF, m4);
            mNL = fmaxf(mNL, fmaxf(ax, fmaxf(ay, az)));
        } else {
            mNF = fmaxf(mNF, m4);
            mNL = fmaxf(mNL, m4);
        }
    }
    #pragma unroll
    for (int off = 32; off; off >>= 1) {
        mA  = fmaxf(mA,  __shfl_down(mA,  off));
        mNF = fmaxf(mNF, __shfl_down(mNF, off));
        mNL = fmaxf(mNL, __shfl_down(mNL, off));
    }
    __shared__ float red[3][16];
    int wid = threadIdx.x >> 6;
    if ((threadIdx.x & 63) == 0) { red[0][wid] = mA; red[1][wid] = mNF; red[2][wid] = mNL; }
    __syncthreads();
    if (threadIdx.x == 0) {
        mA = red[0][0]; mNF = red[1][0]; mNL = red[2][0];
        #pragma unroll
        for (int i = 1; i < 16; ++i) {
            mA  = fmaxf(mA,  red[0][i]);
            mNF = fmaxf(mNF, red[1][i]);
            mNL = fmaxf(mNL, red[2][i]);
        }
        float* p = wsf + (ic*8 + b)*3;
        p[0] = mNL; p[1] = mA; p[2] = mNF;
    }
}

// ---------------- pass 2: scales + quantized A (one tiny block) ----------------
__global__ __launch_bounds__(256) void prep_kernel(const float* __restrict__ w,
                                                   float* __restrict__ wsf,
                                                   unsigned int* __restrict__ wsa) {
    __shared__ float scl[192];
    __shared__ float red[256];
    const int tid = threadIdx.x;
    float ax = 0.0f, aw = 0.0f;
    if (tid < 192) {
        float wsc = 0.0f;
        #pragma unroll 8
        for (int o = 0; o < 64; ++o) wsc = fmaxf(wsc, fabsf(w[o*192 + tid]));
        int ic = tid / 3, k = tid - ic*3;
        float asc = 0.0f;
        #pragma unroll
        for (int b = 0; b < 8; ++b) asc = fmaxf(asc, wsf[(ic*8 + b)*3 + k]);
        float sc = sqrtf(asc) / sqrtf(wsc);    // act**0.5 / w**0.5
        if (sc == 0.0f) sc = 1.0f;
        scl[tid] = sc;
        ax = asc / sc;     // column max of |cols/scale|
        aw = wsc * sc;     // max |w*scale|
    }
    red[tid] = ax; __syncthreads();
    for (int s = 128; s; s >>= 1) { if (tid < s) red[tid] = fmaxf(red[tid], red[tid+s]); __syncthreads(); }
    float axm = red[0]; __syncthreads();
    red[tid] = aw; __syncthreads();
    for (int s = 128; s; s >>= 1) { if (tid < s) red[tid] = fmaxf(red[tid], red[tid+s]); __syncthreads(); }
    float awm = red[0];
    float s_x = (axm == 0.0f) ? 1.0f : axm / QMAXF;
    float s_w = (awm == 0.0f) ? 1.0f : awm / QMAXF;
    if (tid < 192) {                       // rvp[k][ic], k-major
        int k = tid >> 6, ic = tid & 63;
        wsf[1536 + tid] = 1.0f / (scl[3*ic + k] * s_x);
    }
    if (tid == 0)  wsf[1728] = s_x * s_w;
    __syncthreads();
    // quantize weights into k-major A fragments
    for (int idx = tid; idx < 3072; idx += 256) {
        int d = idx & 3, lane = (idx >> 2) & 63, f = idx >> 8;  // f = mt*3+s
        int mt = f / 3, s = f - mt*3;
        int g = lane >> 4, m = lane & 15, oc = mt*16 + m;
        unsigned pk = 0;
        #pragma unroll
        for (int bb = 0; bb < 4; ++bb) {
            int ic = 16*g + 4*d + bb;
            int j = 3*ic + s;
            float q = rintf((w[oc*192 + j] * scl[j]) / s_w);  // ref op order
            q = fminf(fmaxf(q, -QMAXF), QMAXF);
            pk |= (((unsigned)(int)q) & 255u) << (8*bb);
        }
        wsa[idx] = pk;
    }
}

// ---------------- pass 3: conv as i8 MFMA GEMM, NO LDS ----------------
// k-major j' = k*64 + ic: lane (g=lane>>4, tl=lane&15) builds its own B bytes
// from x[16g+4d+bb][t-1+s] -> 16 lane-local unaligned float4 loads per tile.
// Waves fully independent: no barriers, no staging, no bank conflicts.
__global__ __launch_bounds__(256) void conv_mfma_kernel(const float* __restrict__ x,
                                                        const float* __restrict__ bias,
                                                        const float* __restrict__ wsf,
                                                        const v4i* __restrict__ wsa,
                                                        float* __restrict__ out) {
    const int tid  = threadIdx.x;
    const int b    = blockIdx.y;
    const int lane = tid & 63;
    const int wv   = tid >> 6;
    const int g    = lane >> 4;
    const int tl   = lane & 15;
    const int wgid = blockIdx.x * 4 + wv;          // 0..511

    // per-wave constants (L2-hot), hoisted out of the tile loop
    v4i afrag[12];
    #pragma unroll
    for (int i = 0; i < 12; ++i) afrag[i] = wsa[i*64 + lane];

    float rvf[3][16];
    #pragma unroll
    for (int s = 0; s < 3; ++s) {
        #pragma unroll
        for (int d = 0; d < 4; ++d) {
            v4f rv4 = *(const v4f*)&wsf[1536 + s*64 + g*16 + d*4];
            rvf[s][4*d+0] = rv4.x; rvf[s][4*d+1] = rv4.y;
            rvf[s][4*d+2] = rv4.z; rvf[s][4*d+3] = rv4.w;
        }
    }
    const float sxw = wsf[1728];
    v4f bsv[4];
    #pragma unroll
    for (int mt = 0; mt < 4; ++mt) bsv[mt] = *(const v4f*)&bias[mt*16 + g*4];

    const float* xrow = x + (((size_t)(b*64 + g*16)) << 15);   // lane's row block

    for (int it = 0; it < TPW; ++it) {
        const int tg0 = wgid * (TPW*16) + it*16;
        const int t   = tg0 + tl;

        unsigned pk[3][4] = {{0,0,0,0},{0,0,0,0},{0,0,0,0}};
        if (tg0 != 0 && tg0 != L_LEN - 16) {
            // interior: float4 at t-1 covers [t-1..t+2], always in-bounds
            const float* px = xrow + (t - 1);
            #pragma unroll
            for (int r = 0; r < 16; ++r) {
                v4f v = load4u(px + ((size_t)r << 15));
                #pragma unroll
                for (int s = 0; s < 3; ++s) {
                    float xval = (s == 0) ? v.x : (s == 1) ? v.y : v.z;
                    float q = rintf(xval * rvf[s][r]);
                    q = fminf(fmaxf(q, -QMAXF), QMAXF);
                    pk[s][r >> 2] |= (((unsigned)(int)q) & 255u) << (8*(r & 3));
                }
            }
        } else {
            // edge tiles (wave-uniform): clamp load offset, select-fix values
            const int off = (t == 0) ? 0 : ((t >= L_LEN - 3) ? (L_LEN - 4) : (t - 1));
            const bool e0  = (t == 0);
            const bool em2 = (t == L_LEN - 2), em1 = (t == L_LEN - 1);
            const float* px = xrow + off;
            #pragma unroll
            for (int r = 0; r < 16; ++r) {
                v4f v = load4u(px + ((size_t)r << 15));
                float x0 = e0 ? 0.0f : (em2 ? v.y : (em1 ? v.z : v.x));
                float x1 = e0 ? v.x  : (em2 ? v.z : (em1 ? v.w : v.y));
                float x2 = e0 ? v.y  : (em2 ? v.w : (em1 ? 0.0f : v.z));
                #pragma unroll
                for (int s = 0; s < 3; ++s) {
                    float xval = (s == 0) ? x0 : (s == 1) ? x1 : x2;
                    float q = rintf(xval * rvf[s][r]);
                    q = fminf(fmaxf(q, -QMAXF), QMAXF);
                    pk[s][r >> 2] |= (((unsigned)(int)q) & 255u) << (8*(r & 3));
                }
            }
        }

        // ---- MFMA: 3 k-steps, 4 m-tiles ----
        v4i acc[4];
        #pragma unroll
        for (int mt = 0; mt < 4; ++mt) acc[mt] = (v4i){0,0,0,0};
        #pragma unroll
        for (int s = 0; s < 3; ++s) {
            v4i bfv;
            bfv[0] = (int)pk[s][0]; bfv[1] = (int)pk[s][1];
            bfv[2] = (int)pk[s][2]; bfv[3] = (int)pk[s][3];
            #pragma unroll
            for (int mt = 0; mt < 4; ++mt)
                acc[mt] = __builtin_amdgcn_mfma_i32_16x16x64_i8(afrag[mt*3 + s], bfv, acc[mt], 0, 0, 0);
        }

        // ---- epilogue: col=lane&15 -> t, row=(lane>>4)*4+i -> oc ----
        #pragma unroll
        for (int mt = 0; mt < 4; ++mt) {
            #pragma unroll
            for (int i = 0; i < 4; ++i) {
                int oc = mt*16 + g*4 + i;
                out[(((size_t)(b*64 + oc)) << 15) + t] = (float)acc[mt][i] * sxw + bsv[mt][i];
            }
        }
    }
}

extern "C" void kernel_launch(void* const* d_in, const int* in_sizes, int n_in,
                              void* d_out, int out_size, void* d_ws, size_t ws_size,
                              hipStream_t stream) {
    const float* x    = (const float*)d_in[0];
    const float* w    = (const float*)d_in[1];
    const float* bias = (const float*)d_in[2];
    float* out = (float*)d_out;
    float* wsf = (float*)d_ws;
    unsigned int* wsa = (unsigned int*)((char*)d_ws + 8192);

    hipLaunchKernelGGL(actamax_kernel,   dim3(64, 8),  dim3(1024), 0, stream, x, wsf);
    hipLaunchKernelGGL(prep_kernel,      dim3(1),      dim3(256),  0, stream, w, wsf, wsa);
    hipLaunchKernelGGL(conv_mfma_kernel, dim3(128, 8), dim3(256),  0, stream,
                       x, bias, wsf, (const v4i*)wsa, out);
}

// Round 4
// 171.242 us; speedup vs baseline: 1.0207x; 1.0207x over previous
//
#include <hip/hip_runtime.h>

#define L_LEN 32768
#define QMAXF 127.0f
#define TPB 4   // conv tiles (of 64 t) per block

typedef __attribute__((ext_vector_type(4))) int v4i;

// ws layout:
//   wsf[0..1536)    : phase-1 partials [ic][b][k]  (64*8*3)
//   wsf[1536..1728) : rv_j = 1/(scl_j * s_x), j = 3*ic+k (ic-major)
//   wsf[1728]       : s_x * s_w
//   byte 7168       : (u32) block-completion counter (memset to 0 each launch)
//   byte 8192+      : wsa A fragments (quantized weights, i8, MFMA lane-chunk order)

// ---------------- pass 1: amax partials + (last block) fused prep ----------------
__global__ __launch_bounds__(1024) void actamax_prep_kernel(const float* __restrict__ x,
                                                            const float* __restrict__ w,
                                                            float* __restrict__ wsf,
                                                            unsigned int* __restrict__ wsa,
                                                            unsigned int* __restrict__ cnt) {
    const int ic = blockIdx.x, b = blockIdx.y;
    const int tid = threadIdx.x;
    const float4* row = (const float4*)(x + ((size_t)(b*64 + ic) << 15));
    float mA = 0.0f, mNF = 0.0f, mNL = 0.0f;   // all, no-first(t>0), no-last(t<L-1)
    #pragma unroll
    for (int i = 0; i < 8; ++i) {
        int f = tid + (i << 10);
        float4 v = row[f];
        float ax = fabsf(v.x), ay = fabsf(v.y), az = fabsf(v.z), aw = fabsf(v.w);
        float m4 = fmaxf(fmaxf(ax, ay), fmaxf(az, aw));
        mA = fmaxf(mA, m4);
        if (f == 0) {
            mNF = fmaxf(mNF, fmaxf(ay, fmaxf(az, aw)));
            mNL = fmaxf(mNL, m4);
        } else if (f == 8191) {
            mNF = fmaxf(mNF, m4);
            mNL = fmaxf(mNL, fmaxf(ax, fmaxf(ay, az)));
        } else {
            mNF = fmaxf(mNF, m4);
            mNL = fmaxf(mNL, m4);
        }
    }
    #pragma unroll
    for (int off = 32; off; off >>= 1) {
        mA  = fmaxf(mA,  __shfl_down(mA,  off));
        mNF = fmaxf(mNF, __shfl_down(mNF, off));
        mNL = fmaxf(mNL, __shfl_down(mNL, off));
    }
    __shared__ float red[3][16];
    __shared__ int lastf;
    int wid = tid >> 6;
    if ((tid & 63) == 0) { red[0][wid] = mA; red[1][wid] = mNF; red[2][wid] = mNL; }
    __syncthreads();
    if (tid == 0) {
        mA = red[0][0]; mNF = red[1][0]; mNL = red[2][0];
        #pragma unroll
        for (int i = 1; i < 16; ++i) {
            mA  = fmaxf(mA,  red[0][i]);
            mNF = fmaxf(mNF, red[1][i]);
            mNL = fmaxf(mNL, red[2][i]);
        }
        // k=0 uses x[-1..L-2] -> exclude last; k=1 all; k=2 uses x[1..L] -> exclude first
        float* p = wsf + (ic*8 + b)*3;
        p[0] = mNL; p[1] = mA; p[2] = mNF;
        __threadfence();                                   // release partials (agent scope)
        unsigned int t = __hip_atomic_fetch_add(cnt, 1u, __ATOMIC_ACQ_REL,
                                                __HIP_MEMORY_SCOPE_AGENT);
        lastf = (t == 511);
    }
    __syncthreads();
    if (!lastf) return;

    // ---- last finishing block: prep (scales + quantized A fragments) ----
    __threadfence();                                       // acquire: invalidate stale L1/L2
    __shared__ float scl[192];
    __shared__ float redA[16], redW[16];
    __shared__ float bc[2];
    float ax = 0.0f, aw = 0.0f;
    if (tid < 768) {
        int col = tid >> 2, sub = tid & 3;                 // 4 threads per column
        float wsc = 0.0f;
        #pragma unroll
        for (int o = 0; o < 16; ++o) wsc = fmaxf(wsc, fabsf(w[(sub*16 + o)*192 + col]));
        wsc = fmaxf(wsc, __shfl_xor(wsc, 1));              // exact: fmax reassoc
        wsc = fmaxf(wsc, __shfl_xor(wsc, 2));
        if (sub == 0) {
            int ici = col / 3, k = col - ici*3;
            float asc = 0.0f;
            #pragma unroll
            for (int bb = 0; bb < 8; ++bb) asc = fmaxf(asc, wsf[(ici*8 + bb)*3 + k]);
            float sc = sqrtf(asc) / sqrtf(wsc);            // act**0.5 / w**0.5
            if (sc == 0.0f) sc = 1.0f;
            scl[col] = sc;
            ax = asc / sc;                                 // col max of |cols/scale|
            aw = wsc * sc;                                 // max |w*scale|
        }
    }
    #pragma unroll
    for (int off = 32; off; off >>= 1) {
        ax = fmaxf(ax, __shfl_down(ax, off));
        aw = fmaxf(aw, __shfl_down(aw, off));
    }
    if ((tid & 63) == 0) { redA[wid] = ax; redW[wid] = aw; }
    __syncthreads();
    if (tid == 0) {
        float axm = redA[0], awm = redW[0];
        #pragma unroll
        for (int i = 1; i < 16; ++i) { axm = fmaxf(axm, redA[i]); awm = fmaxf(awm, redW[i]); }
        bc[0] = axm; bc[1] = awm;
    }
    __syncthreads();
    const float s_x = (bc[0] == 0.0f) ? 1.0f : bc[0] / QMAXF;
    const float s_w = (bc[1] == 0.0f) ? 1.0f : bc[1] / QMAXF;
    if (tid < 192) wsf[1536 + tid] = 1.0f / (scl[tid] * s_x);
    if (tid == 0)  wsf[1728] = s_x * s_w;
    __syncthreads();
    // quantize weights into MFMA A-fragment (16x16x64 i8) lane-chunk order (ic-major j)
    for (int idx = tid; idx < 3072; idx += 1024) {
        int oc = idx / 48, dwi = idx - oc*48, j0 = dwi*4;
        unsigned pk = 0;
        #pragma unroll
        for (int bb = 0; bb < 4; ++bb) {
            int j = j0 + bb;
            float q = rintf((w[oc*192 + j] * scl[j]) / s_w);  // ref op order
            q = fminf(fmaxf(q, -QMAXF), QMAXF);
            pk |= (((unsigned)(int)q) & 255u) << (8*bb);
        }
        int mt = oc >> 4, m = oc & 15, c = j0 >> 4, s = c >> 2, kq = c & 3;
        wsa[((mt*3 + s)*64 + kq*16 + m)*4 + ((j0 & 15) >> 2)] = pk;
    }
}

// ---------------- pass 2: conv as i8 MFMA GEMM, double-buffered LDS ----------------
// D[oc][t] = sum_j qw[oc][j] * qx[j][t], j = ic*3+k.
// Per tile: quant(regs) -> write bsm[buf] -> ONE barrier -> prefetch next x
// -> ds_read+MFMA -> store. Buffer i&1 alternation makes the leading
// "reads drained" barrier unnecessary (tile-i barrier orders reuse 2 tiles later).
// Granule XOR swizzle G^=(G>>6)&7 on both sides: writes 2-way (free), reads
// stay a permutation within 8-lane groups (conflict-free).
__global__ __launch_bounds__(256) void conv_mfma_kernel(const float* __restrict__ x,
                                                        const float* __restrict__ bias,
                                                        const float* __restrict__ wsf,
                                                        const v4i* __restrict__ wsa,
                                                        float* __restrict__ out) {
    __shared__ int bsm[2][3072];
    const int tid  = threadIdx.x;
    const int b    = blockIdx.y;
    const int lane = tid & 63;
    const int wv   = tid >> 6;

    // per-thread staging roles
    const int tq  = tid & 15;      // owns t = 4*tq .. 4*tq+3 (tile-local)
    const int icg = tid >> 4;      // owns ic = 4*icg .. 4*icg+3  (j = 12*icg..+11)
    const int tb  = tq << 2;

    // first tile's x loads issued first (longest latency)
    float xv[4][6];                // [ici][t-1 .. t+4]
    {
        const int t0 = (blockIdx.x * TPB) << 6;
        #pragma unroll
        for (int ici = 0; ici < 4; ++ici) {
            const float* rowp = x + (((size_t)(b*64 + icg*4 + ici)) << 15) + t0 + tb;
            float4 mid = *(const float4*)rowp;
            float lm = (t0 + tb > 0)           ? rowp[-1] : 0.0f;
            float rp = (t0 + tb + 4 < L_LEN)   ? rowp[4]  : 0.0f;
            xv[ici][0] = lm;    xv[ici][1] = mid.x; xv[ici][2] = mid.y;
            xv[ici][3] = mid.z; xv[ici][4] = mid.w; xv[ici][5] = rp;
        }
    }

    // A fragments: 4 m-tiles x 3 k-steps (L2-hot)
    v4i afrag[12];
    #pragma unroll
    for (int i = 0; i < 12; ++i) afrag[i] = wsa[i*64 + lane];

    float rv[12];
    #pragma unroll
    for (int jj = 0; jj < 12; ++jj) rv[jj] = wsf[1536 + icg*12 + jj];
    const float sxw = wsf[1728];

    for (int it = 0; it < TPB; ++it) {
        const int t0c = (blockIdx.x * TPB + it) << 6;
        const int buf = it & 1;

        // quantize current tile from xv into registers (consumes xv)
        unsigned pkq[12];
        #pragma unroll
        for (int dt = 0; dt < 4; ++dt) {
            #pragma unroll
            for (int dw = 0; dw < 3; ++dw) {
                unsigned pk = 0;
                #pragma unroll
                for (int bb = 0; bb < 4; ++bb) {
                    int jloc = dw*4 + bb;           // j = 12*icg + jloc = 3*ic + k
                    int ici = jloc / 3, k = jloc - ici*3;
                    float q = rintf(xv[ici][dt + k] * rv[jloc]);
                    q = fminf(fmaxf(q, -QMAXF), QMAXF);
                    pk |= (((unsigned)(int)q) & 255u) << (8*bb);
                }
                pkq[dt*3 + dw] = pk;
            }
        }

        // write into this tile's buffer (other buffer may still be read)
        #pragma unroll
        for (int dt = 0; dt < 4; ++dt) {
            int t = tb + dt, wt = t >> 4, n = t & 15;
            #pragma unroll
            for (int dw = 0; dw < 3; ++dw) {
                int j0 = icg*12 + dw*4;
                int c = j0 >> 4, s = c >> 2, kq = c & 3;
                int G = (wt*3 + s)*64 + kq*16 + n;
                G ^= (G >> 6) & 7;                 // bank swizzle
                bsm[buf][G*4 + ((j0 & 15) >> 2)] = (int)pkq[dt*3 + dw];
            }
        }
        __syncthreads();                           // single barrier per tile

        // prefetch next tile's x (in flight across MFMA + epilogue)
        if (it + 1 < TPB) {
            const int t0n = (blockIdx.x * TPB + it + 1) << 6;
            #pragma unroll
            for (int ici = 0; ici < 4; ++ici) {
                const float* rowp = x + (((size_t)(b*64 + icg*4 + ici)) << 15) + t0n + tb;
                float4 mid = *(const float4*)rowp;
                float lm = (t0n + tb > 0)          ? rowp[-1] : 0.0f;
                float rp = (t0n + tb + 4 < L_LEN)  ? rowp[4]  : 0.0f;
                xv[ici][0] = lm;    xv[ici][1] = mid.x; xv[ici][2] = mid.y;
                xv[ici][3] = mid.z; xv[ici][4] = mid.w; xv[ici][5] = rp;
            }
        }

        // ---- MFMA ----
        v4i acc[4];
        #pragma unroll
        for (int mt = 0; mt < 4; ++mt) acc[mt] = (v4i){0,0,0,0};
        const v4i* bsmv = (const v4i*)bsm[buf];
        #pragma unroll
        for (int s = 0; s < 3; ++s) {
            int Gr = (wv*3 + s)*64 + lane;
            Gr ^= (wv*3 + s) & 7;                  // same swizzle ((Gr>>6)&7)
            v4i bf = bsmv[Gr];
            #pragma unroll
            for (int mt = 0; mt < 4; ++mt)
                acc[mt] = __builtin_amdgcn_mfma_i32_16x16x64_i8(afrag[mt*3 + s], bf, acc[mt], 0, 0, 0);
        }

        // ---- epilogue: C/D layout col=lane&15 -> t, row=(lane>>4)*4+i -> oc ----
        const int tg   = t0c + (wv << 4) + (lane & 15);
        const int rowq = (lane >> 4) << 2;
        #pragma unroll
        for (int mt = 0; mt < 4; ++mt) {
            #pragma unroll
            for (int i = 0; i < 4; ++i) {
                int oc = mt*16 + rowq + i;
                out[(((size_t)(b*64 + oc)) << 15) + tg] = (float)acc[mt][i] * sxw + bias[oc];
            }
        }
    }
}

extern "C" void kernel_launch(void* const* d_in, const int* in_sizes, int n_in,
                              void* d_out, int out_size, void* d_ws, size_t ws_size,
                              hipStream_t stream) {
    const float* x    = (const float*)d_in[0];
    const float* w    = (const float*)d_in[1];
    const float* bias = (const float*)d_in[2];
    float* out = (float*)d_out;
    float* wsf = (float*)d_ws;
    unsigned int* wsa = (unsigned int*)((char*)d_ws + 8192);
    unsigned int* cnt = (unsigned int*)((char*)d_ws + 7168);

    hipMemsetAsync(cnt, 0, 4, stream);   // zero completion counter (capturable)
    hipLaunchKernelGGL(actamax_prep_kernel, dim3(64, 8),  dim3(1024), 0, stream,
                       x, w, wsf, wsa, cnt);
    hipLaunchKernelGGL(conv_mfma_kernel,    dim3(128, 8), dim3(256),  0, stream,
                       x, bias, wsf, (const v4i*)wsa, out);
}

// Round 5
// 152.086 us; speedup vs baseline: 1.1492x; 1.1259x over previous
//
#include <hip/hip_runtime.h>

#define L_LEN 32768
#define QMAXF 127.0f
#define TPB 4   // conv tiles (of 64 t) per block

typedef __attribute__((ext_vector_type(4))) int v4i;

// ws layout:
//   wsf[0..1536)    : phase-1 partials [ic][b][k] (64*8*3) — atomicMax'd, memset to 0 per launch
//   wsf[1536..1728) : rv_j = 1/(scl_j * s_x), j = 3*ic+k (ic-major)
//   wsf[1728]       : s_x * s_w
//   byte 8192+      : wsa A fragments (quantized weights, i8, MFMA lane-chunk order)

// |x| >= +0.0 always, so uint-compare of IEEE bit patterns == float compare:
__device__ inline void amax_atomic(float* p, float v) {
    atomicMax((unsigned int*)p, __float_as_uint(v));
}

// ---------------- pass 1: per-(ic,b) abs-max partials ----------------
// 4 blocks per row (quarter-row each), 256 threads, 8 float4/thread batched
// into registers (guaranteed 8-deep MLP), wave reduce + 3 atomicMax.
__global__ __launch_bounds__(256) void actamax_kernel(const float* __restrict__ x,
                                                      float* __restrict__ wsf) {
    const int ic = blockIdx.x, b = blockIdx.y, ch = blockIdx.z;
    const int tid = threadIdx.x;
    const float4* row = (const float4*)(x + ((size_t)(b*64 + ic) << 15));
    const int base = ch*2048 + tid;

    float4 vbuf[8];
    #pragma unroll
    for (int i = 0; i < 8; ++i) vbuf[i] = row[base + i*256];   // all 8 issued up front

    float mA = 0.0f, mNF = 0.0f, mNL = 0.0f;   // all, no-first(t>0), no-last(t<L-1)
    #pragma unroll
    for (int i = 0; i < 8; ++i) {
        const int f = base + i*256;
        float4 v = vbuf[i];
        float ax = fabsf(v.x), ay = fabsf(v.y), az = fabsf(v.z), aw = fabsf(v.w);
        float m4 = fmaxf(fmaxf(ax, ay), fmaxf(az, aw));
        mA = fmaxf(mA, m4);
        if (f == 0) {                      // only ch==0,i==0,tid==0
            mNF = fmaxf(mNF, fmaxf(ay, fmaxf(az, aw)));
            mNL = fmaxf(mNL, m4);
        } else if (f == 8191) {            // only ch==3,i==7,tid==255
            mNF = fmaxf(mNF, m4);
            mNL = fmaxf(mNL, fmaxf(ax, fmaxf(ay, az)));
        } else {
            mNF = fmaxf(mNF, m4);
            mNL = fmaxf(mNL, m4);
        }
    }
    #pragma unroll
    for (int off = 32; off; off >>= 1) {
        mA  = fmaxf(mA,  __shfl_down(mA,  off));
        mNF = fmaxf(mNF, __shfl_down(mNF, off));
        mNL = fmaxf(mNL, __shfl_down(mNL, off));
    }
    __shared__ float red[3][4];
    const int wid = tid >> 6;
    if ((tid & 63) == 0) { red[0][wid] = mA; red[1][wid] = mNF; red[2][wid] = mNL; }
    __syncthreads();
    if (tid == 0) {
        mA  = fmaxf(fmaxf(red[0][0], red[0][1]), fmaxf(red[0][2], red[0][3]));
        mNF = fmaxf(fmaxf(red[1][0], red[1][1]), fmaxf(red[1][2], red[1][3]));
        mNL = fmaxf(fmaxf(red[2][0], red[2][1]), fmaxf(red[2][2], red[2][3]));
        // k=0 uses x[-1..L-2] -> exclude last; k=1 all; k=2 uses x[1..L] -> exclude first
        float* p = wsf + (ic*8 + b)*3;
        amax_atomic(p + 0, mNL);
        amax_atomic(p + 1, mA);
        amax_atomic(p + 2, mNF);
    }
}

// ---------------- pass 2: one tiny block computes scales + quantized A ----------------
__global__ __launch_bounds__(256) void prep_kernel(const float* __restrict__ w,
                                                   float* __restrict__ wsf,
                                                   unsigned int* __restrict__ wsa) {
    __shared__ float scl[192];
    __shared__ float red[256];
    const int tid = threadIdx.x;
    float ax = 0.0f, aw = 0.0f;
    if (tid < 192) {
        float wsc = 0.0f;
        #pragma unroll 8
        for (int o = 0; o < 64; ++o) wsc = fmaxf(wsc, fabsf(w[o*192 + tid]));
        int ic = tid / 3, k = tid - ic*3;
        float asc = 0.0f;
        #pragma unroll
        for (int b = 0; b < 8; ++b) asc = fmaxf(asc, wsf[(ic*8 + b)*3 + k]);
        float sc = sqrtf(asc) / sqrtf(wsc);    // act**0.5 / w**0.5
        if (sc == 0.0f) sc = 1.0f;
        scl[tid] = sc;
        ax = asc / sc;     // column max of |cols/scale| (monotone fp div)
        aw = wsc * sc;     // max |w*scale|
    }
    red[tid] = ax; __syncthreads();
    for (int s = 128; s; s >>= 1) { if (tid < s) red[tid] = fmaxf(red[tid], red[tid+s]); __syncthreads(); }
    float axm = red[0]; __syncthreads();
    red[tid] = aw; __syncthreads();
    for (int s = 128; s; s >>= 1) { if (tid < s) red[tid] = fmaxf(red[tid], red[tid+s]); __syncthreads(); }
    float awm = red[0];
    float s_x = (axm == 0.0f) ? 1.0f : axm / QMAXF;
    float s_w = (awm == 0.0f) ? 1.0f : awm / QMAXF;
    if (tid < 192) wsf[1536 + tid] = 1.0f / (scl[tid] * s_x);
    if (tid == 0)  wsf[1728] = s_x * s_w;
    __syncthreads();
    // quantize weights into MFMA A-fragment (16x16x64 i8) lane-chunk order
    for (int idx = tid; idx < 3072; idx += 256) {
        int oc = idx / 48, dwi = idx - oc*48, j0 = dwi*4;
        unsigned pk = 0;
        #pragma unroll
        for (int bb = 0; bb < 4; ++bb) {
            int j = j0 + bb;
            float q = rintf((w[oc*192 + j] * scl[j]) / s_w);  // ref op order
            q = fminf(fmaxf(q, -QMAXF), QMAXF);
            pk |= (((unsigned)(int)q) & 255u) << (8*bb);
        }
        int mt = oc >> 4, m = oc & 15, c = j0 >> 4, s = c >> 2, kq = c & 3;
        wsa[((mt*3 + s)*64 + kq*16 + m)*4 + ((j0 & 15) >> 2)] = pk;
    }
}

// ---------------- pass 3: conv as i8 MFMA GEMM, double-buffered LDS ----------------
// Per tile: quant(regs) -> write bsm[buf] -> ONE barrier -> prefetch next x
// -> ds_read+MFMA -> store. Buffer alternation removes the leading barrier
// (tile-i barrier orders reuse two tiles later; compiler drains lgkm at barrier).
// Granule XOR swizzle G^=(G>>6)&7 both sides: writes 2-way (free), reads a
// permutation within 8-lane groups (conflict-free).
__global__ __launch_bounds__(256) void conv_mfma_kernel(const float* __restrict__ x,
                                                        const float* __restrict__ bias,
                                                        const float* __restrict__ wsf,
                                                        const v4i* __restrict__ wsa,
                                                        float* __restrict__ out) {
    __shared__ int bsm[2][3072];
    const int tid  = threadIdx.x;
    const int b    = blockIdx.y;
    const int lane = tid & 63;
    const int wv   = tid >> 6;

    // per-thread staging roles
    const int tq  = tid & 15;      // owns t = 4*tq .. 4*tq+3 (tile-local)
    const int icg = tid >> 4;      // owns ic = 4*icg .. 4*icg+3  (j = 12*icg..+11)
    const int tb  = tq << 2;

    // first tile's x loads issued first (longest latency)
    float xv[4][6];                // [ici][t-1 .. t+4]
    {
        const int t0 = (blockIdx.x * TPB) << 6;
        #pragma unroll
        for (int ici = 0; ici < 4; ++ici) {
            const float* rowp = x + (((size_t)(b*64 + icg*4 + ici)) << 15) + t0 + tb;
            float4 mid = *(const float4*)rowp;
            float lm = (t0 + tb > 0)           ? rowp[-1] : 0.0f;
            float rp = (t0 + tb + 4 < L_LEN)   ? rowp[4]  : 0.0f;
            xv[ici][0] = lm;    xv[ici][1] = mid.x; xv[ici][2] = mid.y;
            xv[ici][3] = mid.z; xv[ici][4] = mid.w; xv[ici][5] = rp;
        }
    }

    // A fragments: 4 m-tiles x 3 k-steps (L2-hot)
    v4i afrag[12];
    #pragma unroll
    for (int i = 0; i < 12; ++i) afrag[i] = wsa[i*64 + lane];

    float rv[12];
    #pragma unroll
    for (int jj = 0; jj < 12; ++jj) rv[jj] = wsf[1536 + icg*12 + jj];
    const float sxw = wsf[1728];

    for (int it = 0; it < TPB; ++it) {
        const int t0c = (blockIdx.x * TPB + it) << 6;
        const int buf = it & 1;

        // quantize current tile from xv into registers (consumes xv)
        unsigned pkq[12];
        #pragma unroll
        for (int dt = 0; dt < 4; ++dt) {
            #pragma unroll
            for (int dw = 0; dw < 3; ++dw) {
                unsigned pk = 0;
                #pragma unroll
                for (int bb = 0; bb < 4; ++bb) {
                    int jloc = dw*4 + bb;           // j = 12*icg + jloc = 3*ic + k
                    int ici = jloc / 3, k = jloc - ici*3;
                    float q = rintf(xv[ici][dt + k] * rv[jloc]);
                    q = fminf(fmaxf(q, -QMAXF), QMAXF);
                    pk |= (((unsigned)(int)q) & 255u) << (8*bb);
                }
                pkq[dt*3 + dw] = pk;
            }
        }

        // write into this tile's buffer (other buffer may still be read)
        #pragma unroll
        for (int dt = 0; dt < 4; ++dt) {
            int t = tb + dt, wt = t >> 4, n = t & 15;
            #pragma unroll
            for (int dw = 0; dw < 3; ++dw) {
                int j0 = icg*12 + dw*4;
                int c = j0 >> 4, s = c >> 2, kq = c & 3;
                int G = (wt*3 + s)*64 + kq*16 + n;
                G ^= (G >> 6) & 7;                 // bank swizzle
                bsm[buf][G*4 + ((j0 & 15) >> 2)] = (int)pkq[dt*3 + dw];
            }
        }
        __syncthreads();                           // single barrier per tile

        // prefetch next tile's x (in flight across MFMA + epilogue)
        if (it + 1 < TPB) {
            const int t0n = (blockIdx.x * TPB + it + 1) << 6;
            #pragma unroll
            for (int ici = 0; ici < 4; ++ici) {
                const float* rowp = x + (((size_t)(b*64 + icg*4 + ici)) << 15) + t0n + tb;
                float4 mid = *(const float4*)rowp;
                float lm = (t0n + tb > 0)          ? rowp[-1] : 0.0f;
                float rp = (t0n + tb + 4 < L_LEN)  ? rowp[4]  : 0.0f;
                xv[ici][0] = lm;    xv[ici][1] = mid.x; xv[ici][2] = mid.y;
                xv[ici][3] = mid.z; xv[ici][4] = mid.w; xv[ici][5] = rp;
            }
        }

        // ---- MFMA ----
        v4i acc[4];
        #pragma unroll
        for (int mt = 0; mt < 4; ++mt) acc[mt] = (v4i){0,0,0,0};
        const v4i* bsmv = (const v4i*)bsm[buf];
        #pragma unroll
        for (int s = 0; s < 3; ++s) {
            int Gr = (wv*3 + s)*64 + lane;
            Gr ^= (wv*3 + s) & 7;                  // same swizzle ((Gr>>6)&7)
            v4i bf = bsmv[Gr];
            #pragma unroll
            for (int mt = 0; mt < 4; ++mt)
                acc[mt] = __builtin_amdgcn_mfma_i32_16x16x64_i8(afrag[mt*3 + s], bf, acc[mt], 0, 0, 0);
        }

        // ---- epilogue: C/D layout col=lane&15 -> t, row=(lane>>4)*4+i -> oc ----
        const int tg   = t0c + (wv << 4) + (lane & 15);
        const int rowq = (lane >> 4) << 2;
        #pragma unroll
        for (int mt = 0; mt < 4; ++mt) {
            #pragma unroll
            for (int i = 0; i < 4; ++i) {
                int oc = mt*16 + rowq + i;
                out[(((size_t)(b*64 + oc)) << 15) + tg] = (float)acc[mt][i] * sxw + bias[oc];
            }
        }
    }
}

extern "C" void kernel_launch(void* const* d_in, const int* in_sizes, int n_in,
                              void* d_out, int out_size, void* d_ws, size_t ws_size,
                              hipStream_t stream) {
    const float* x    = (const float*)d_in[0];
    const float* w    = (const float*)d_in[1];
    const float* bias = (const float*)d_in[2];
    float* out = (float*)d_out;
    float* wsf = (float*)d_ws;
    unsigned int* wsa = (unsigned int*)((char*)d_ws + 8192);

    hipMemsetAsync(wsf, 0, 6144, stream);             // zero amax partials
    hipLaunchKernelGGL(actamax_kernel,   dim3(64, 8, 4), dim3(256), 0, stream, x, wsf);
    hipLaunchKernelGGL(prep_kernel,      dim3(1),        dim3(256), 0, stream, w, wsf, wsa);
    hipLaunchKernelGGL(conv_mfma_kernel, dim3(128, 8),   dim3(256), 0, stream,
                       x, bias, wsf, (const v4i*)wsa, out);
}